// Round 14
// baseline (115.042 us; speedup 1.0000x reference)
//
#include <hip/hip_runtime.h>
#include <stdint.h>

// out[c,b,d] = sum_a in[a,b] * W[reg[c],a,d] + bias[reg[c],d]
#define A_DIM 512   // in_features  (K)
#define B_DIM 1024  // batch        (M)
#define D_DIM 512   // out_features (N)
#define NKT   16    // K-tiles of 32

typedef __bf16 bf16x8 __attribute__((ext_vector_type(8)));
typedef float f32x4 __attribute__((ext_vector_type(4)));
typedef float f32x2 __attribute__((ext_vector_type(2)));
typedef unsigned u32x2 __attribute__((ext_vector_type(2)));

typedef __attribute__((address_space(1))) void gvoid_t;
typedef __attribute__((address_space(3))) void svoid_t;

#define WAITV12() asm volatile("s_waitcnt vmcnt(12)" ::: "memory")
#define WAITV0()  asm volatile("s_waitcnt vmcnt(0)" ::: "memory")
#define LGKM0()   asm volatile("s_waitcnt lgkmcnt(0)" ::: "memory")
#define FENCE()   asm volatile("" ::: "memory")
#define BARRIER() do { FENCE(); __builtin_amdgcn_s_barrier(); FENCE(); } while (0)

// fp32 -> bf16 RNE (proven R1/R3/R5) — used in the prepass
__device__ __forceinline__ unsigned short f2bf(float f) {
  union { float f; unsigned u; } x; x.f = f;
  unsigned r = x.u + 0x7fffu + ((x.u >> 16) & 1u);
  return (unsigned short)(r >> 16);
}

// packed fp32 pair -> bf16x2 in one VALU op (lo = src0, hi = src1)
__device__ __forceinline__ unsigned pk2(float lo, float hi) {
  unsigned r;
  asm("v_cvt_pk_bf16_f32 %0, %1, %2" : "=v"(r) : "v"(lo), "v"(hi));
  return r;
}

__device__ __forceinline__ void gload16(const void* g, void* l) {
  __builtin_amdgcn_global_load_lds((gvoid_t*)g, (svoid_t*)l, 16, 0, 0);
}

// ---------------------------------------------------------------------------
// Prepass (X only): Xt[b][a] <- bf16(input[a][b]). R1-proven verbatim.
// ---------------------------------------------------------------------------
__global__ __launch_bounds__(256) void transpose_cvt(
    const float* __restrict__ src, unsigned short* __restrict__ dst,
    int M, int N) {
  __shared__ float T[64][65];
  const int t = threadIdx.x;
  const int m0 = blockIdx.y * 64, n0 = blockIdx.x * 64;

#pragma unroll
  for (int p = 0; p < 4; ++p) {
    const int mr = (t >> 4) + p * 16;
    const int n4 = (t & 15) * 4;
    const float4 v = *(const float4*)(src + (size_t)(m0 + mr) * N + n0 + n4);
    T[n4 + 0][mr] = v.x;
    T[n4 + 1][mr] = v.y;
    T[n4 + 2][mr] = v.z;
    T[n4 + 3][mr] = v.w;
  }
  __syncthreads();

#pragma unroll
  for (int p = 0; p < 2; ++p) {
    const int nr = (t >> 3) + p * 32;
    const int m8 = (t & 7) * 8;
    alignas(16) unsigned short tmp[8];
#pragma unroll
    for (int j = 0; j < 8; ++j) tmp[j] = f2bf(T[nr][m8 + j]);
    *(uint4*)(dst + (size_t)(n0 + nr) * M + m0 + m8) = *(const uint4*)tmp;
  }
}

// ---------------------------------------------------------------------------
// Fused GEMM = R13 with a kp-pair B layout: Bsu[2][8][264],
// addr(kp,d) = (kp>>1)*264 + 2d + (kp&1).
//  - B fragment reads: 2 x b64 per n (8 instr/wave/tile, was 16 b32)
//  - writeB: 2 x uint4 stores (was 4), rows 16B-aligned (264*4 % 16 == 0)
//  - W loads: 8 x float2/thread (wave covers one 512B row-run, coalesced)
//  - vmcnt: 12 ops/tile (4 gload_lds + 8 dwordx2), 2 tiles in flight
// k-packing (pk2(k even, k odd); u[i] = kp 4lg+i) identical to R13.
// ---------------------------------------------------------------------------
__global__ __launch_bounds__(256, 2) void mlgemm_fused(
    const unsigned short* __restrict__ Xt, const float* __restrict__ wtab,
    const float* __restrict__ bias_table, const int* __restrict__ regions,
    float* __restrict__ out) {
  __shared__ union SM {
    struct {
      alignas(16) unsigned short As[3][256][32];  // 48 KiB
      alignas(16) unsigned Bsu[2][8][264];        // 16.5 KiB
    } k;
    alignas(16) float slab[4][32 * 68];           // 34 KiB (epilogue reuse)
  } sm;

  // XCD-chunked decode: b0 varies fastest -> 4 consecutive blocks share one
  // W panel in their XCD's L2 (R10 proved this reuse is worth ~23 us).
  const int bid = blockIdx.x;
  const int xcd = bid & 7, q = bid >> 3;
  const int c   = (q >> 4) * 8 + xcd;
  const int t16 = q & 15;
  const int b0     = (t16 & 3) * 256;
  const int d0blk  = (t16 >> 2) * 128;

  const int t = threadIdx.x;
  const int w = t >> 6, l = t & 63;
  const int lr = l & 15, lg = l >> 4;
  const int wm = w >> 1, wn = w & 1;             // 2 (M) x 2 (N) waves
  const int h = regions[c];

  const unsigned short* Xbase = Xt + (size_t)b0 * A_DIM;
  const float* Wbase = wtab + (size_t)h * A_DIM * D_DIM + d0blk;

  f32x4 acc[8][4] = {};

  const int a_src_chunk = (l & 3) ^ ((l >> 3) & 3);
  const int a_lrow = l >> 2;

  // B loader: this wave owns kp-quad rows w and w+4; lane covers d = 2l, 2l+1.
  f32x2 bregE[8], bregO[8];

  auto issueA = [&](int T) {
    const int buf = T % 3;
    const int koff = T * 32 + a_src_chunk * 8;
#pragma unroll
    for (int i = 0; i < 4; ++i) {
      const int row0 = w * 64 + i * 16;
      gload16(Xbase + (size_t)(row0 + a_lrow) * A_DIM + koff, &sm.k.As[buf][row0][0]);
    }
  };
  auto ldB = [&](int T, f32x2 (&L)[8]) {
#pragma unroll
    for (int half = 0; half < 2; ++half) {
      const int r = w + half * 4;                 // kp-quad row (0..7)
#pragma unroll
      for (int j = 0; j < 4; ++j) {
        const float* p = Wbase + (size_t)(T * 32 + 4 * r + j) * D_DIM + 2 * l;
        L[half * 4 + j] = *(const f32x2*)p;       // {W[k][2l], W[k][2l+1]}
      }
    }
  };
  auto writeB = [&](int T, f32x2 (&L)[8]) {
#pragma unroll
    for (int half = 0; half < 2; ++half) {
      const int r = w + half * 4;
      const f32x2* Lq = &L[half * 4];
      uint4 u;
      u.x = pk2(Lq[0].x, Lq[1].x);   // (kpE, d')  : k = 4r, 4r+1
      u.y = pk2(Lq[2].x, Lq[3].x);   // (kpO, d')  : k = 4r+2, 4r+3
      u.z = pk2(Lq[0].y, Lq[1].y);   // (kpE, d'+1)
      u.w = pk2(Lq[2].y, Lq[3].y);   // (kpO, d'+1)
      *(uint4*)&sm.k.Bsu[T & 1][r][4 * l] = u;    // words 2d'..2d'+3
    }
  };

  auto mfmaStep = [&](int T) {
    const int abuf = T % 3, bbuf = T & 1;
    bf16x8 av[8], bv[4];
#pragma unroll
    for (int m = 0; m < 8; ++m) {
      const int row = wm * 128 + m * 16 + lr;
      av[m] = *(const bf16x8*)&sm.k.As[abuf][row][(lg ^ ((lr >> 1) & 3)) * 8];
    }
#pragma unroll
    for (int n = 0; n < 4; ++n) {
      const int d = wn * 64 + n * 16 + lr;
      union { u32x2 p[2]; bf16x8 v; } ub;
      ub.p[0] = *(const u32x2*)&sm.k.Bsu[bbuf][2 * lg][2 * d];      // kp 4lg,4lg+1
      ub.p[1] = *(const u32x2*)&sm.k.Bsu[bbuf][2 * lg + 1][2 * d];  // kp 4lg+2,+3
      bv[n] = ub.v;
    }
    __builtin_amdgcn_s_setprio(1);
#pragma unroll
    for (int m = 0; m < 8; ++m)
#pragma unroll
      for (int n = 0; n < 4; ++n)
        acc[m][n] = __builtin_amdgcn_mfma_f32_16x16x32_bf16(av[m], bv[n], acc[m][n], 0, 0, 0);
    __builtin_amdgcn_s_setprio(0);
  };

  // Bias in prologue.
  float bs[4];
#pragma unroll
  for (int n = 0; n < 4; ++n)
    bs[n] = bias_table[(size_t)h * D_DIM + d0blk + wn * 64 + n * 16 + lr];

  // Prologue: 2 tiles in flight (12 VMEM/wave/tile: 4 gload_lds + 8 dwordx2).
  issueA(0); ldB(0, bregE);
  issueA(1); ldB(1, bregO);

  // R9/R13-proven loop order: wait T -> writeB(T) -> barrier -> issue T+2 -> mfma.
#pragma unroll 1
  for (int T = 0; T < NKT - 2; T += 2) {
    WAITV12();                      // tile T's 12 done; T+1's stay in flight
    writeB(T, bregE);
    LGKM0(); BARRIER();
    issueA(T + 2); ldB(T + 2, bregE); FENCE();
    mfmaStep(T);

    WAITV12();
    writeB(T + 1, bregO);
    LGKM0(); BARRIER();
    issueA(T + 3); ldB(T + 3, bregO); FENCE();
    mfmaStep(T + 1);
  }
  WAITV12();
  writeB(NKT - 2, bregE);
  LGKM0(); BARRIER();
  mfmaStep(NKT - 2);
  WAITV0();
  writeB(NKT - 1, bregO);
  LGKM0(); BARRIER();
  mfmaStep(NKT - 1);

  // ---- Epilogue: R9-proven slab -> nontemporal full-line stores ----
  __syncthreads();   // all waves done reading As/Bsu before slab aliasing

  float* ob = out + (size_t)c * B_DIM * D_DIM;
  const int orow_base = b0 + wm * 128;
  const int ocol_base = d0blk + wn * 64;
#pragma unroll
  for (int g = 0; g < 4; ++g) {
#pragma unroll
    for (int m2 = 0; m2 < 2; ++m2)
#pragma unroll
      for (int j = 0; j < 4; ++j) {
        const int row = m2 * 16 + lg * 4 + j;     // 0..31
#pragma unroll
        for (int n = 0; n < 4; ++n)
          sm.slab[w][row * 68 + n * 16 + lr] = acc[g * 2 + m2][n][j] + bs[n];
      }
    __syncthreads();   // cross-lane exchange (R6 fix)
#pragma unroll
    for (int r = 0; r < 8; ++r) {
      const int chunk = r * 64 + l;               // 0..511
      const int row = chunk >> 4, seg = chunk & 15;
      const f32x4 v = *(const f32x4*)&sm.slab[w][row * 68 + seg * 4];
      __builtin_nontemporal_store(
          v, (f32x4*)(ob + (size_t)(orow_base + g * 32 + row) * D_DIM +
                      ocol_base + seg * 4));
    }
    __syncthreads();   // slab reused next group
  }
}

// ---------------------------------------------------------------------------
// Fallback: naive fp32 (only if ws can't hold Xt).
// ---------------------------------------------------------------------------
__global__ __launch_bounds__(256) void naive_ml(
    const float* __restrict__ in, const int* __restrict__ regions,
    const float* __restrict__ wt, const float* __restrict__ bias,
    float* __restrict__ out) {
  const int d = blockIdx.x * 256 + threadIdx.x;
  const int b = blockIdx.y;
  const int cz = blockIdx.z;
  const int hh = regions[cz];
  const float* W = wt + (size_t)hh * A_DIM * D_DIM + d;
  float acc = bias[(size_t)hh * D_DIM + d];
  for (int a = 0; a < A_DIM; ++a) acc += in[(size_t)a * B_DIM + b] * W[(size_t)a * D_DIM];
  out[(size_t)cz * B_DIM * D_DIM + (size_t)b * D_DIM + d] = acc;
}

extern "C" void kernel_launch(void* const* d_in, const int* in_sizes, int n_in,
                              void* d_out, int out_size, void* d_ws, size_t ws_size,
                              hipStream_t stream) {
  const float* input = (const float*)d_in[0];
  const int* regions = (const int*)d_in[1];
  const float* wtab  = (const float*)d_in[2];
  const float* btab  = (const float*)d_in[3];
  float* out = (float*)d_out;
  const int C = in_sizes[1];  // n_regions = 128

  const size_t xt_bytes = (size_t)B_DIM * A_DIM * 2;  // 1 MB

  if (ws_size < xt_bytes) {
    naive_ml<<<dim3(D_DIM / 256, B_DIM, C), 256, 0, stream>>>(input, regions, wtab, btab, out);
    return;
  }

  unsigned short* Xt = (unsigned short*)d_ws;

  transpose_cvt<<<dim3(B_DIM / 64, A_DIM / 64), 256, 0, stream>>>(
      input, Xt, A_DIM, B_DIM);
  mlgemm_fused<<<dim3((B_DIM / 256) * (D_DIM / 128) * C), 256, 0, stream>>>(
      Xt, wtab, btab, regions, out);
}